// Round 7
// baseline (294.863 us; speedup 1.0000x reference)
//
#include <hip/hip_runtime.h>
#include <hip/hip_bf16.h>
#include <math.h>

typedef __bf16 bf16;
typedef __bf16 bf16x8 __attribute__((ext_vector_type(8)));
typedef float  f32x4  __attribute__((ext_vector_type(4)));

#define MFMA16(a,b,c) __builtin_amdgcn_mfma_f32_16x16x32_bf16((a),(b),(c),0,0,0)
#define ATT_SCALE_LOG2E 0.0637587160330163f  /* (1/sqrt(512)) * log2(e) */

// async global->LDS, 16 B/lane; LDS dest = wave-uniform base + lane*16
__device__ __forceinline__ void async16p(const void* g, void* l) {
    __builtin_amdgcn_global_load_lds((const __attribute__((address_space(1))) void*)g,
                                     (__attribute__((address_space(3))) void*)l,
                                     16, 0, 0);
}

// -------- prep: cvt Q,K fp32->bf16; transpose 4 weights -> bf16 T[n][k] ----
__global__ __launch_bounds__(256) void prep_kernel(
    const float* __restrict__ Q, const float* __restrict__ K,
    const float* __restrict__ Wq, const float* __restrict__ Wk,
    const float* __restrict__ Wv, const float* __restrict__ Wo,
    bf16* __restrict__ Qb, bf16* __restrict__ Kb,
    bf16* __restrict__ WqT, bf16* __restrict__ WkT,
    bf16* __restrict__ WvT, bf16* __restrict__ WoT)
{
    __shared__ float tile[32][33];
    const int bx = blockIdx.x;
    if (bx < 8192) {
        const float* src = (bx < 4096) ? Q : K;
        bf16* dst        = (bx < 4096) ? Qb : Kb;
        int i = ((bx & 4095) * 256 + threadIdx.x) * 8;
        float4 a = *(const float4*)(src + i);
        float4 b = *(const float4*)(src + i + 4);
        bf16x8 o;
        o[0]=(bf16)a.x; o[1]=(bf16)a.y; o[2]=(bf16)a.z; o[3]=(bf16)a.w;
        o[4]=(bf16)b.x; o[5]=(bf16)b.y; o[6]=(bf16)b.z; o[7]=(bf16)b.w;
        *(bf16x8*)(dst + i) = o;
    } else {
        const int wid = bx - 8192;
        const float* W; bf16* T;
        switch (wid >> 8) {
          case 0: W=Wq; T=WqT; break;
          case 1: W=Wk; T=WkT; break;
          case 2: W=Wv; T=WvT; break;
          default: W=Wo; T=WoT; break;
        }
        const int rest = wid & 255;
        const int k0 = (rest & 15) * 32, n0 = (rest >> 4) * 32;
        const int tx = threadIdx.x & 31, ty = threadIdx.x >> 5;
        #pragma unroll
        for (int i=0;i<32;i+=8)
            tile[ty+i][tx] = W[(size_t)(k0+ty+i)*512 + n0+tx];
        __syncthreads();
        #pragma unroll
        for (int i=0;i<32;i+=8)
            T[(size_t)(n0+ty+i)*512 + k0+tx] = (bf16)tile[tx][ty+i];
    }
}

// -------- shared GEMM K-loop: 128x128 tile, BK=64, async16 staging ---------
// Each async16p issue covers 32 rows x 64 el = 2048 elements; wave w's slice
// is rows w*8..w*8+7 = 512 elements.  (r6 bug: these offsets were in BYTES.)
__device__ __forceinline__ void gemm_core(
    const bf16* __restrict__ A, const bf16* __restrict__ BT,
    int m0, int n0, char* smem, f32x4 (&acc)[4][4])
{
    bf16* As = (bf16*)smem;            // 128 x 64
    bf16* Bs = (bf16*)(smem + 16384);  // 128 x 64
    const int tid = threadIdx.x;
    const int lane = tid & 63, wave = tid >> 6;
    const int qd = lane >> 4, lr = lane & 15;
    const int wm = (wave & 1) * 64, wn = (wave >> 1) * 64;

    const int srow = tid >> 3;                       // 0..31
    const int sgr  = ((tid & 7) ^ (srow & 7)) * 8;   // swizzled global granule
    const bf16* gA = A  + (size_t)(m0 + srow)*512 + sgr;
    const bf16* gB = BT + (size_t)(n0 + srow)*512 + sgr;
    bf16* lA = As + wave*512;   // wave-uniform; lane adds 16 B
    bf16* lB = Bs + wave*512;

    for (int k0 = 0; k0 < 512; k0 += 64) {
        __syncthreads();
        #pragma unroll
        for (int i=0;i<4;i++) {
            async16p(gA + k0 + (size_t)i*32*512, lA + i*2048);
            async16p(gB + k0 + (size_t)i*32*512, lB + i*2048);
        }
        __syncthreads();
        #pragma unroll
        for (int half=0; half<2; ++half) {
            bf16x8 af[4], bfr[4];
            #pragma unroll
            for (int mi=0;mi<4;mi++) {
                int row = wm + mi*16 + lr;
                af[mi] = *(bf16x8*)(As + row*64 + (((half*4+qd)^(lr&7))*8));
            }
            #pragma unroll
            for (int ni=0;ni<4;ni++) {
                int row = wn + ni*16 + lr;
                bfr[ni] = *(bf16x8*)(Bs + row*64 + (((half*4+qd)^(lr&7))*8));
            }
            #pragma unroll
            for (int mi=0;mi<4;mi++)
              #pragma unroll
              for (int ni=0;ni<4;ni++)
                acc[mi][ni] = MFMA16(af[mi], bfr[ni], acc[mi][ni]);
        }
    }
}

// ------------- projection GEMM: z=0 q->qbb, z=1 k->kbb, z=2 v->vT ----------
__global__ __launch_bounds__(256, 4) void gemm_qkv_kernel(
    const bf16* __restrict__ Qb, const bf16* __restrict__ Kb,
    const bf16* __restrict__ WqT, const bf16* __restrict__ WkT,
    const bf16* __restrict__ WvT,
    const float* __restrict__ bq, const float* __restrict__ bk,
    const float* __restrict__ bv,
    bf16* __restrict__ qbb, bf16* __restrict__ kbb, bf16* __restrict__ vT)
{
    __shared__ __align__(16) char smem[32768];
    const int z = blockIdx.z;
    const bf16* A  = (z == 0) ? Qb  : Kb;
    const bf16* BT = (z == 0) ? WqT : (z == 1) ? WkT : WvT;
    const float* bb = (z == 0) ? bq : (z == 1) ? bk  : bv;
    const int m0 = blockIdx.x * 128, n0 = blockIdx.y * 128;
    const int tid = threadIdx.x;
    const int lane = tid & 63, wave = tid >> 6;
    const int qd = lane >> 4, lr = lane & 15;
    const int wm = (wave & 1) * 64, wn = (wave >> 1) * 64;

    f32x4 acc[4][4];
    #pragma unroll
    for (int i=0;i<4;i++)
      #pragma unroll
      for (int j=0;j<4;j++) acc[i][j] = (f32x4){0,0,0,0};

    gemm_core(A, BT, m0, n0, smem, acc);

    if (z < 2) {
        bf16* C = (z == 0) ? qbb : kbb;
        #pragma unroll
        for (int ni=0;ni<4;ni++) {
            int n = n0 + wn + ni*16 + lr;
            float bv0 = bb[n];
            #pragma unroll
            for (int mi=0;mi<4;mi++) {
                int mb = m0 + wm + mi*16 + qd*4;
                #pragma unroll
                for (int r=0;r<4;r++)
                    C[(size_t)(mb+r)*512 + n] = (bf16)(acc[mi][ni][r] + bv0);
            }
        }
    } else {   // v -> vT[b][h][d][tok] via swizzled LDS transpose (overlays As)
        bf16* Lt = (bf16*)smem;   // 64 x 128
        const int b = m0 >> 10, tok0 = m0 & 1023;
        const int row = tid >> 2, ch = tid & 3;
        #pragma unroll
        for (int half = 0; half < 2; ++half) {
            __syncthreads();
            if ((wn >> 6) == half) {
                #pragma unroll
                for (int ni=0;ni<4;ni++) {
                    int nl = ni*16 + lr;
                    float bvv = bb[n0 + half*64 + nl];
                    #pragma unroll
                    for (int mi=0;mi<4;mi++)
                      #pragma unroll
                      for (int r=0;r<4;r++) {
                        int col = wm + mi*16 + qd*4 + r;
                        Lt[nl*128 + ((((col>>3)^(nl&7))<<3) | (col&7))]
                            = (bf16)(acc[mi][ni][r] + bvv);
                      }
                }
            }
            __syncthreads();
            const int h = (n0 >> 6) + half;
            bf16* dst = vT + ((size_t)((b*8 + h)*64 + row))*1024 + tok0 + ch*32;
            #pragma unroll
            for (int s=0;s<4;s++) {
                int g = (ch*4 + s) ^ (row & 7);
                *(uint4*)(dst + s*8) = *(uint4*)(Lt + row*128 + g*8);
            }
        }
    }
}

// ---------------- attention: 128 q-rows/block, reg-prefetch K/V staging ----
__global__ __launch_bounds__(256, 4) void attn_kernel(
    const bf16* __restrict__ qb, const bf16* __restrict__ kb,
    const bf16* __restrict__ vT, bf16* __restrict__ attnb)
{
    const int qt = blockIdx.x, h = blockIdx.y, b = blockIdx.z;
    const int tid = threadIdx.x, lane = tid & 63, wave = tid >> 6;
    const int qd = lane >> 4, lr = lane & 15;
    const int q0 = qt*128 + wave*32;

    __shared__ bf16 Ks[64*64];
    __shared__ bf16 Vs[64*64];
    __shared__ bf16 Pl[4][32][72];

    bf16x8 aq[2][2];
    #pragma unroll
    for (int mi=0;mi<2;mi++) {
        const bf16* qrow = qb + ((size_t)(b*1024 + q0 + mi*16 + lr))*512 + h*64;
        aq[mi][0] = *(const bf16x8*)(qrow + qd*8);
        aq[mi][1] = *(const bf16x8*)(qrow + 32 + qd*8);
    }

    const int srow = tid >> 2;
    const int c2 = (tid & 3) * 2;
    const int wg0 = ((c2  ) ^ (srow & 7)) * 8;
    const int wg1 = ((c2+1) ^ (srow & 7)) * 8;
    const bf16* kgp = kb + ((size_t)(b*1024 + srow))*512 + h*64 + c2*8;
    const bf16* vgp = vT + ((size_t)((b*8 + h)*64 + srow))*1024 + c2*8;

    uint4 k0r = *(const uint4*)(kgp);
    uint4 k1r = *(const uint4*)(kgp + 8);
    uint4 v0r = *(const uint4*)(vgp);
    uint4 v1r = *(const uint4*)(vgp + 8);

    f32x4 acc[2][4];
    #pragma unroll
    for (int mi=0;mi<2;mi++)
      #pragma unroll
      for (int ni=0;ni<4;ni++) acc[mi][ni] = (f32x4){0,0,0,0};
    float l[2][4] = {{0,0,0,0},{0,0,0,0}};

    for (int t=0; t<16; ++t) {
        __syncthreads();
        *(uint4*)(&Ks[srow*64 + wg0]) = k0r;
        *(uint4*)(&Ks[srow*64 + wg1]) = k1r;
        *(uint4*)(&Vs[srow*64 + wg0]) = v0r;
        *(uint4*)(&Vs[srow*64 + wg1]) = v1r;
        __syncthreads();
        if (t < 15) {   // prefetch next tile; overlaps compute below
            const size_t kk = (size_t)(t+1)*64;
            k0r = *(const uint4*)(kgp + kk*512);
            k1r = *(const uint4*)(kgp + kk*512 + 8);
            v0r = *(const uint4*)(vgp + kk);
            v1r = *(const uint4*)(vgp + kk + 8);
        }

        f32x4 s[2][4];
        #pragma unroll
        for (int mi=0;mi<2;mi++)
          #pragma unroll
          for (int ni=0;ni<4;ni++) s[mi][ni] = (f32x4){0,0,0,0};
        #pragma unroll
        for (int ni=0;ni<4;ni++) {
            int row = ni*16 + lr;
            bf16x8 b0 = *(bf16x8*)(Ks + row*64 + (((qd  )^(lr&7))*8));
            bf16x8 b1 = *(bf16x8*)(Ks + row*64 + (((qd+4)^(lr&7))*8));
            #pragma unroll
            for (int mi=0;mi<2;mi++) {
                s[mi][ni] = MFMA16(aq[mi][0], b0, s[mi][ni]);
                s[mi][ni] = MFMA16(aq[mi][1], b1, s[mi][ni]);
            }
        }
        #pragma unroll
        for (int mi=0;mi<2;mi++)
          #pragma unroll
          for (int ni=0;ni<4;ni++)
            #pragma unroll
            for (int r=0;r<4;r++) {
                float pv = exp2f(s[mi][ni][r] * ATT_SCALE_LOG2E);
                s[mi][ni][r] = pv;
                l[mi][r] += pv;
            }
        #pragma unroll
        for (int mi=0;mi<2;mi++)
          #pragma unroll
          for (int ni=0;ni<4;ni++)
            #pragma unroll
            for (int r=0;r<4;r++)
                Pl[wave][mi*16 + qd*4 + r][ni*16 + lr] = (bf16)s[mi][ni][r];
        bf16x8 ap[2][2];
        #pragma unroll
        for (int mi=0;mi<2;mi++) {
            ap[mi][0] = *(bf16x8*)(&Pl[wave][mi*16+lr][qd*8]);
            ap[mi][1] = *(bf16x8*)(&Pl[wave][mi*16+lr][32+qd*8]);
        }
        #pragma unroll
        for (int ni=0;ni<4;ni++) {
            int row = ni*16 + lr;
            bf16x8 v0 = *(bf16x8*)(Vs + row*64 + (((qd  )^(lr&7))*8));
            bf16x8 v1 = *(bf16x8*)(Vs + row*64 + (((qd+4)^(lr&7))*8));
            #pragma unroll
            for (int mi=0;mi<2;mi++) {
                acc[mi][ni] = MFMA16(ap[mi][0], v0, acc[mi][ni]);
                acc[mi][ni] = MFMA16(ap[mi][1], v1, acc[mi][ni]);
            }
        }
    }

    #pragma unroll
    for (int off=1; off<16; off<<=1)
      #pragma unroll
      for (int mi=0;mi<2;mi++)
        #pragma unroll
        for (int r=0;r<4;r++) l[mi][r] += __shfl_xor(l[mi][r], off);

    #pragma unroll
    for (int mi=0;mi<2;mi++) {
        float inv[4];
        #pragma unroll
        for (int r=0;r<4;r++) inv[r] = 1.f / l[mi][r];
        #pragma unroll
        for (int ni=0;ni<4;ni++)
          #pragma unroll
          for (int r=0;r<4;r++)
            Pl[wave][qd*4+r][ni*16+lr] = (bf16)(acc[mi][ni][r] * inv[r]);
        bf16x8 oA = *(bf16x8*)(&Pl[wave][lr][qd*8]);
        bf16x8 oB = *(bf16x8*)(&Pl[wave][lr][32+qd*8]);
        bf16* dst = attnb + ((size_t)(b*1024 + q0 + mi*16 + lr))*512 + h*64;
        *(bf16x8*)(dst + qd*8)      = oA;
        *(bf16x8*)(dst + 32 + qd*8) = oB;
    }
}

// ---------------- ln0: Obf = LN(q + attn)  (bf16 in/out) -------------------
__global__ __launch_bounds__(256) void ln0_kernel(
    const bf16* __restrict__ qbb, const bf16* __restrict__ attnb,
    bf16* __restrict__ Obf)
{
    const int wave = threadIdx.x >> 6, lane = threadIdx.x & 63;
    const int row = blockIdx.x*4 + wave;
    const size_t base = (size_t)row*512 + lane*8;
    bf16x8 qv = *(const bf16x8*)(qbb + base);
    bf16x8 av = *(const bf16x8*)(attnb + base);
    float x[8];
    #pragma unroll
    for (int i=0;i<8;i++) x[i] = (float)qv[i] + (float)av[i];
    float s1 = 0.f, s2 = 0.f;
    #pragma unroll
    for (int i=0;i<8;i++){ s1 += x[i]; s2 += x[i]*x[i]; }
    #pragma unroll
    for (int off=1; off<64; off<<=1) { s1 += __shfl_xor(s1, off); s2 += __shfl_xor(s2, off); }
    float mu  = s1 * (1.f/512.f);
    float var = s2 * (1.f/512.f) - mu*mu;
    float rstd = rsqrtf(var + 1e-5f);
    bf16x8 ob;
    #pragma unroll
    for (int i=0;i<8;i++) ob[i] = (bf16)((x[i]-mu)*rstd);
    *(bf16x8*)(Obf + base) = ob;
}

// ------- gemm_o: G = Obf@WoT + bo; xb = Obf + gelu(G)  (bf16 out) ----------
__global__ __launch_bounds__(256, 4) void gemm_o_kernel(
    const bf16* __restrict__ Obf, const bf16* __restrict__ WoT,
    const float* __restrict__ bo, bf16* __restrict__ xb)
{
    __shared__ __align__(16) char smem[32768];
    const int m0 = blockIdx.x * 128, n0 = blockIdx.y * 128;
    const int tid = threadIdx.x;
    const int lane = tid & 63, wave = tid >> 6;
    const int qd = lane >> 4, lr = lane & 15;
    const int wm = (wave & 1) * 64, wn = (wave >> 1) * 64;

    f32x4 acc[4][4];
    #pragma unroll
    for (int i=0;i<4;i++)
      #pragma unroll
      for (int j=0;j<4;j++) acc[i][j] = (f32x4){0,0,0,0};

    gemm_core(Obf, WoT, m0, n0, smem, acc);

    #pragma unroll
    for (int ni=0;ni<4;ni++) {
        int n = n0 + wn + ni*16 + lr;
        float bv = bo[n];
        #pragma unroll
        for (int mi=0;mi<4;mi++) {
            int mb = m0 + wm + mi*16 + qd*4;
            #pragma unroll
            for (int r=0;r<4;r++) {
                float g = acc[mi][ni][r] + bv;
                float gelu = 0.5f * g * (1.f + erff(g * 0.70710678118654752f));
                size_t idx = (size_t)(mb+r)*512 + n;
                xb[idx] = (bf16)((float)Obf[idx] + gelu);
            }
        }
    }
}

// ---------------- ln1: out = LN(xb) ----------------
__global__ __launch_bounds__(256) void ln1_kernel(
    const bf16* __restrict__ xb, float* __restrict__ out)
{
    const int wave = threadIdx.x >> 6, lane = threadIdx.x & 63;
    const int row = blockIdx.x*4 + wave;
    const size_t base = (size_t)row*512 + lane*8;
    bf16x8 xv = *(const bf16x8*)(xb + base);
    float x[8];
    #pragma unroll
    for (int i=0;i<8;i++) x[i] = (float)xv[i];
    float s1 = 0.f, s2 = 0.f;
    #pragma unroll
    for (int i=0;i<8;i++){ s1 += x[i]; s2 += x[i]*x[i]; }
    #pragma unroll
    for (int off=1; off<64; off<<=1) { s1 += __shfl_xor(s1, off); s2 += __shfl_xor(s2, off); }
    float mu  = s1 * (1.f/512.f);
    float var = s2 * (1.f/512.f) - mu*mu;
    float rstd = rsqrtf(var + 1e-5f);
    float4 o0 = {(x[0]-mu)*rstd,(x[1]-mu)*rstd,(x[2]-mu)*rstd,(x[3]-mu)*rstd};
    float4 o1 = {(x[4]-mu)*rstd,(x[5]-mu)*rstd,(x[6]-mu)*rstd,(x[7]-mu)*rstd};
    *(float4*)(out + base)     = o0;
    *(float4*)(out + base + 4) = o1;
}

extern "C" void kernel_launch(void* const* d_in, const int* in_sizes, int n_in,
                              void* d_out, int out_size, void* d_ws, size_t ws_size,
                              hipStream_t stream)
{
    (void)in_sizes; (void)n_in; (void)out_size; (void)ws_size;
    const float* Q  = (const float*)d_in[0];
    const float* K  = (const float*)d_in[1];
    const float* Wq = (const float*)d_in[2];
    const float* bq = (const float*)d_in[3];
    const float* Wk = (const float*)d_in[4];
    const float* bk = (const float*)d_in[5];
    const float* Wv = (const float*)d_in[6];
    const float* bv = (const float*)d_in[7];
    const float* Wo = (const float*)d_in[8];
    const float* bo = (const float*)d_in[9];
    float* out = (float*)d_out;

    const size_t nTok = (size_t)16*1024*512;
    char* p = (char*)d_ws;
    auto alloc = [&](size_t bytes)->char* {
        char* r = p; p += (bytes + 255) & ~(size_t)255; return r;
    };
    bf16* Qb    = (bf16*)alloc(nTok*2);
    bf16* Kb    = (bf16*)alloc(nTok*2);
    bf16* WqT   = (bf16*)alloc(512*512*2);
    bf16* WkT   = (bf16*)alloc(512*512*2);
    bf16* WvT   = (bf16*)alloc(512*512*2);
    bf16* WoT   = (bf16*)alloc(512*512*2);
    bf16* qbb   = (bf16*)alloc(nTok*2);
    bf16* kbb   = (bf16*)alloc(nTok*2);
    bf16* vT    = (bf16*)alloc(nTok*2);
    bf16* attnb = (bf16*)alloc(nTok*2);
    bf16* Obf   = (bf16*)alloc(nTok*2);
    bf16* xb    = (bf16*)alloc(nTok*2);

    prep_kernel<<<9216, 256, 0, stream>>>(Q, K, Wq, Wk, Wv, Wo,
                                          Qb, Kb, WqT, WkT, WvT, WoT);
    gemm_qkv_kernel<<<dim3(128,4,3), 256, 0, stream>>>(Qb, Kb, WqT, WkT, WvT,
                                                       bq, bk, bv, qbb, kbb, vT);
    attn_kernel<<<dim3(8,8,16), 256, 0, stream>>>(qbb, kbb, vT, attnb);
    ln0_kernel<<<4096, 256, 0, stream>>>(qbb, attnb, Obf);
    gemm_o_kernel<<<dim3(128,4), 256, 0, stream>>>(Obf, WoT, bo, xb);
    ln1_kernel<<<4096, 256, 0, stream>>>(xb, out);
}

// Round 8
// 270.643 us; speedup vs baseline: 1.0895x; 1.0895x over previous
//
#include <hip/hip_runtime.h>
#include <hip/hip_bf16.h>
#include <math.h>

typedef __bf16 bf16;
typedef __bf16 bf16x8 __attribute__((ext_vector_type(8)));
typedef float  f32x4  __attribute__((ext_vector_type(4)));

#define MFMA16(a,b,c) __builtin_amdgcn_mfma_f32_16x16x32_bf16((a),(b),(c),0,0,0)
#define ATT_SCALE 0.0441941738241592f  /* 1/sqrt(512) */

// async global->LDS, 16 B/lane; LDS dest = wave-uniform base + lane*16
__device__ __forceinline__ void async16p(const void* g, void* l) {
    __builtin_amdgcn_global_load_lds((const __attribute__((address_space(1))) void*)g,
                                     (__attribute__((address_space(3))) void*)l,
                                     16, 0, 0);
}

// ---------------- prep: transpose 4 weights fp32[k][n] -> bf16 T[n][k] -----
__global__ __launch_bounds__(256) void prep_w_kernel(
    const float* __restrict__ Wq, const float* __restrict__ Wk,
    const float* __restrict__ Wv, const float* __restrict__ Wo,
    bf16* __restrict__ WqT, bf16* __restrict__ WkT,
    bf16* __restrict__ WvT, bf16* __restrict__ WoT)
{
    __shared__ float tile[32][33];
    const int bx = blockIdx.x;
    const float* W; bf16* T;
    switch (bx >> 8) {
      case 0: W=Wq; T=WqT; break;
      case 1: W=Wk; T=WkT; break;
      case 2: W=Wv; T=WvT; break;
      default: W=Wo; T=WoT; break;
    }
    const int rest = bx & 255;
    const int k0 = (rest & 15) * 32, n0 = (rest >> 4) * 32;
    const int tx = threadIdx.x & 31, ty = threadIdx.x >> 5;
    #pragma unroll
    for (int i=0;i<32;i+=8)
        tile[ty+i][tx] = W[(size_t)(k0+ty+i)*512 + n0+tx];
    __syncthreads();
    #pragma unroll
    for (int i=0;i<32;i+=8)
        T[(size_t)(n0+ty+i)*512 + k0+tx] = (bf16)tile[tx][ty+i];
}

// ------------- projection GEMM: fp32 A staged async, bf16 weights ----------
// z=0: q=Q@Wq+bq -> qbb ; z=1: k=K@Wk+bk -> kbb ; z=2: v=K@Wv+bv -> vT.
// 128x128 tile, BK=32, (256,3).  (r5's measured-best non-attn pipeline.)
__global__ __launch_bounds__(256, 3) void gemm_qkv_kernel(
    const float* __restrict__ Qf, const float* __restrict__ Kf,
    const bf16* __restrict__ WqT, const bf16* __restrict__ WkT,
    const bf16* __restrict__ WvT,
    const float* __restrict__ bq, const float* __restrict__ bk,
    const float* __restrict__ bv,
    bf16* __restrict__ qbb, bf16* __restrict__ kbb, bf16* __restrict__ vT)
{
    __shared__ __align__(16) char smem[24576];
    float* As32 = (float*)smem;            // 128x32 fp32 = 16 KB
    bf16*  Bs   = (bf16*)(smem + 16384);   // 128x32 bf16 = 8 KB
    bf16*  Lt   = (bf16*)smem;             // 64x128 bf16 (overlays As32, epilogue only)

    const int z = blockIdx.z;
    const float* A  = (z == 0) ? Qf  : Kf;
    const bf16*  BT = (z == 0) ? WqT : (z == 1) ? WkT : WvT;
    const float* bb = (z == 0) ? bq  : (z == 1) ? bk  : bv;

    const int m0 = blockIdx.x * 128, n0 = blockIdx.y * 128;
    const int tid = threadIdx.x;
    const int lane = tid & 63, wave = tid >> 6;
    const int qd = lane >> 4, lr = lane & 15;
    const int wm = (wave & 1) * 64, wn = (wave >> 1) * 64;

    const float* gA = A + (size_t)(m0 + (tid>>3))*512 + (((tid&7)^((tid>>3)&7))*4);
    float* lA = As32 + wave*256;
    const bf16* gB = BT + (size_t)(n0 + (tid>>2))*512 + (((tid&3)^((tid>>2)&3))*8);
    bf16* lB = Bs + wave*512;

    f32x4 acc[4][4];
    #pragma unroll
    for (int i=0;i<4;i++)
      #pragma unroll
      for (int j=0;j<4;j++) acc[i][j] = (f32x4){0,0,0,0};

    for (int k0 = 0; k0 < 512; k0 += 32) {
        __syncthreads();
        #pragma unroll
        for (int i=0;i<4;i++)
            async16p(gA + k0 + (size_t)i*32*512, lA + i*1024);
        async16p(gB + k0,          lB);
        async16p(gB + k0 + 64*512, lB + 2048);
        __syncthreads();
        bf16x8 af[4], bfr[4];
        #pragma unroll
        for (int mi=0;mi<4;mi++) {
            int row = wm + mi*16 + lr;
            f32x4 f0 = *(f32x4*)(As32 + row*32 + (((qd*2  )^(lr&7))*4));
            f32x4 f1 = *(f32x4*)(As32 + row*32 + (((qd*2+1)^(lr&7))*4));
            bf16x8 a;
            a[0]=(bf16)f0[0]; a[1]=(bf16)f0[1]; a[2]=(bf16)f0[2]; a[3]=(bf16)f0[3];
            a[4]=(bf16)f1[0]; a[5]=(bf16)f1[1]; a[6]=(bf16)f1[2]; a[7]=(bf16)f1[3];
            af[mi] = a;
        }
        #pragma unroll
        for (int ni=0;ni<4;ni++)
            bfr[ni] = *(bf16x8*)(Bs + (wn+ni*16+lr)*32 + ((qd^(lr&3))*8));
        #pragma unroll
        for (int mi=0;mi<4;mi++)
          #pragma unroll
          for (int ni=0;ni<4;ni++)
            acc[mi][ni] = MFMA16(af[mi], bfr[ni], acc[mi][ni]);
    }

    if (z < 2) {   // q or k: direct bf16 row-major write
        bf16* C = (z == 0) ? qbb : kbb;
        #pragma unroll
        for (int ni=0;ni<4;ni++) {
            int n = n0 + wn + ni*16 + lr;
            float bv0 = bb[n];
            #pragma unroll
            for (int mi=0;mi<4;mi++) {
                int mb = m0 + wm + mi*16 + qd*4;
                #pragma unroll
                for (int r=0;r<4;r++)
                    C[(size_t)(mb+r)*512 + n] = (bf16)(acc[mi][ni][r] + bv0);
            }
        }
    } else {       // v: vT[b][h][d][tok] via swizzled LDS transpose
        const int b = m0 >> 10, tok0 = m0 & 1023;
        const int row = tid >> 2, ch = tid & 3;
        #pragma unroll
        for (int half = 0; half < 2; ++half) {
            __syncthreads();
            if ((wn >> 6) == half) {
                #pragma unroll
                for (int ni=0;ni<4;ni++) {
                    int nl = ni*16 + lr;
                    float bvv = bb[n0 + half*64 + nl];
                    #pragma unroll
                    for (int mi=0;mi<4;mi++)
                      #pragma unroll
                      for (int r=0;r<4;r++) {
                        int col = wm + mi*16 + qd*4 + r;
                        Lt[nl*128 + ((((col>>3)^(nl&7))<<3) | (col&7))]
                            = (bf16)(acc[mi][ni][r] + bvv);
                      }
                }
            }
            __syncthreads();
            const int h = (n0 >> 6) + half;
            bf16* dst = vT + ((size_t)((b*8 + h)*64 + row))*1024 + tok0 + ch*32;
            #pragma unroll
            for (int s=0;s<4;s++) {
                int g = (ch*4 + s) ^ (row & 7);
                *(uint4*)(dst + s*8) = *(uint4*)(Lt + row*128 + g*8);
            }
        }
    }
}

// ---------------- attention: r3 structure (measured best) + q-residual -----
// 128 q-rows/block (4 waves x 32), 16 k-tiles of 64; padded-72 LDS, register
// round-trip staging with cross-tile prefetch; __expf; epilogue adds q so
// attnb holds q+attn (ln0 becomes single-input).
__global__ __launch_bounds__(256, 4) void attn_kernel(
    const bf16* __restrict__ qb, const bf16* __restrict__ kb,
    const bf16* __restrict__ vT, bf16* __restrict__ attnb)
{
    const int qt = blockIdx.x, h = blockIdx.y, b = blockIdx.z;
    const int tid = threadIdx.x, lane = tid & 63, wave = tid >> 6;
    const int qd = lane >> 4, lr = lane & 15;
    const int q0 = qt*128 + wave*32;

    __shared__ bf16 Ks[64][72];      // [key][d]
    __shared__ bf16 Vs[64][72];      // [d][key]
    __shared__ bf16 Pl[4][32][72];   // per-wave P round-trip (C->A layout)

    bf16x8 aq[2][2];
    #pragma unroll
    for (int mi=0;mi<2;mi++) {
        const bf16* qrow = qb + ((size_t)(b*1024 + q0 + mi*16 + lr))*512 + h*64;
        aq[mi][0] = *(const bf16x8*)(qrow + qd*8);
        aq[mi][1] = *(const bf16x8*)(qrow + 32 + qd*8);
    }

    const int srow = tid >> 2;
    const int scol = (tid & 3) * 16;
    const bf16* kgp = kb + ((size_t)(b*1024 + srow))*512 + h*64 + scol;
    const bf16* vgp = vT + ((size_t)((b*8 + h)*64 + srow))*1024 + scol;

    uint4 k0r = *(const uint4*)(kgp);
    uint4 k1r = *(const uint4*)(kgp + 8);
    uint4 v0r = *(const uint4*)(vgp);
    uint4 v1r = *(const uint4*)(vgp + 8);

    f32x4 acc[2][4];
    #pragma unroll
    for (int mi=0;mi<2;mi++)
      #pragma unroll
      for (int ni=0;ni<4;ni++) acc[mi][ni] = (f32x4){0,0,0,0};
    float l[2][4] = {{0,0,0,0},{0,0,0,0}};

    for (int t=0; t<16; ++t) {
        __syncthreads();
        *(uint4*)(&Ks[srow][scol])   = k0r;
        *(uint4*)(&Ks[srow][scol+8]) = k1r;
        *(uint4*)(&Vs[srow][scol])   = v0r;
        *(uint4*)(&Vs[srow][scol+8]) = v1r;
        __syncthreads();
        if (t < 15) {   // prefetch next tile; overlaps compute below
            const size_t kk = (size_t)(t+1)*64;
            k0r = *(const uint4*)(kgp + kk*512);
            k1r = *(const uint4*)(kgp + kk*512 + 8);
            v0r = *(const uint4*)(vgp + kk);
            v1r = *(const uint4*)(vgp + kk + 8);
        }

        f32x4 s[2][4];
        #pragma unroll
        for (int mi=0;mi<2;mi++)
          #pragma unroll
          for (int ni=0;ni<4;ni++) s[mi][ni] = (f32x4){0,0,0,0};
        #pragma unroll
        for (int ni=0;ni<4;ni++) {
            bf16x8 b0 = *(bf16x8*)(&Ks[ni*16+lr][qd*8]);
            bf16x8 b1 = *(bf16x8*)(&Ks[ni*16+lr][32+qd*8]);
            #pragma unroll
            for (int mi=0;mi<2;mi++) {
                s[mi][ni] = MFMA16(aq[mi][0], b0, s[mi][ni]);
                s[mi][ni] = MFMA16(aq[mi][1], b1, s[mi][ni]);
            }
        }
        #pragma unroll
        for (int mi=0;mi<2;mi++)
          #pragma unroll
          for (int ni=0;ni<4;ni++)
            #pragma unroll
            for (int r=0;r<4;r++) {
                float pv = __expf(s[mi][ni][r] * ATT_SCALE);
                s[mi][ni][r] = pv;
                l[mi][r] += pv;
            }
        #pragma unroll
        for (int mi=0;mi<2;mi++)
          #pragma unroll
          for (int ni=0;ni<4;ni++)
            #pragma unroll
            for (int r=0;r<4;r++)
                Pl[wave][mi*16 + qd*4 + r][ni*16 + lr] = (bf16)s[mi][ni][r];
        bf16x8 ap[2][2];
        #pragma unroll
        for (int mi=0;mi<2;mi++) {
            ap[mi][0] = *(bf16x8*)(&Pl[wave][mi*16+lr][qd*8]);
            ap[mi][1] = *(bf16x8*)(&Pl[wave][mi*16+lr][32+qd*8]);
        }
        #pragma unroll
        for (int ni=0;ni<4;ni++) {
            bf16x8 v0 = *(bf16x8*)(&Vs[ni*16+lr][qd*8]);
            bf16x8 v1 = *(bf16x8*)(&Vs[ni*16+lr][32+qd*8]);
            #pragma unroll
            for (int mi=0;mi<2;mi++) {
                acc[mi][ni] = MFMA16(ap[mi][0], v0, acc[mi][ni]);
                acc[mi][ni] = MFMA16(ap[mi][1], v1, acc[mi][ni]);
            }
        }
    }

    #pragma unroll
    for (int off=1; off<16; off<<=1)
      #pragma unroll
      for (int mi=0;mi<2;mi++)
        #pragma unroll
        for (int r=0;r<4;r++) l[mi][r] += __shfl_xor(l[mi][r], off);

    // epilogue: normalize, transpose via Pl, add q (residual), store bf16x8
    #pragma unroll
    for (int mi=0;mi<2;mi++) {
        float inv[4];
        #pragma unroll
        for (int r=0;r<4;r++) inv[r] = 1.f / l[mi][r];
        #pragma unroll
        for (int ni=0;ni<4;ni++)
          #pragma unroll
          for (int r=0;r<4;r++)
            Pl[wave][qd*4+r][ni*16+lr] = (bf16)(acc[mi][ni][r] * inv[r]);
        bf16x8 oA = *(bf16x8*)(&Pl[wave][lr][qd*8]);
        bf16x8 oB = *(bf16x8*)(&Pl[wave][lr][32+qd*8]);
        bf16x8 rA, rB;
        #pragma unroll
        for (int j=0;j<8;j++) {
            rA[j] = (bf16)((float)oA[j] + (float)aq[mi][0][j]);
            rB[j] = (bf16)((float)oB[j] + (float)aq[mi][1][j]);
        }
        bf16* dst = attnb + ((size_t)(b*1024 + q0 + mi*16 + lr))*512 + h*64;
        *(bf16x8*)(dst + qd*8)      = rA;
        *(bf16x8*)(dst + 32 + qd*8) = rB;
    }
}

// ---------------- ln0: Obf = LN(attnb)  (attnb already holds q+attn) -------
__global__ __launch_bounds__(256) void ln0_kernel(
    const bf16* __restrict__ attnb, bf16* __restrict__ Obf)
{
    const int wave = threadIdx.x >> 6, lane = threadIdx.x & 63;
    const int row = blockIdx.x*4 + wave;
    const size_t base = (size_t)row*512 + lane*8;
    bf16x8 av = *(const bf16x8*)(attnb + base);
    float x[8];
    #pragma unroll
    for (int i=0;i<8;i++) x[i] = (float)av[i];
    float s1 = 0.f, s2 = 0.f;
    #pragma unroll
    for (int i=0;i<8;i++){ s1 += x[i]; s2 += x[i]*x[i]; }
    #pragma unroll
    for (int off=1; off<64; off<<=1) { s1 += __shfl_xor(s1, off); s2 += __shfl_xor(s2, off); }
    float mu  = s1 * (1.f/512.f);
    float var = s2 * (1.f/512.f) - mu*mu;
    float rstd = rsqrtf(var + 1e-5f);
    bf16x8 ob;
    #pragma unroll
    for (int i=0;i<8;i++) ob[i] = (bf16)((x[i]-mu)*rstd);
    *(bf16x8*)(Obf + base) = ob;
}

// -------- shared GEMM K-loop: 128x128 tile, BK=64, async16 staging ---------
__device__ __forceinline__ void gemm_core(
    const bf16* __restrict__ A, const bf16* __restrict__ BT,
    int m0, int n0, char* smem, f32x4 (&acc)[4][4])
{
    bf16* As = (bf16*)smem;            // 128 x 64
    bf16* Bs = (bf16*)(smem + 16384);  // 128 x 64
    const int tid = threadIdx.x;
    const int lane = tid & 63, wave = tid >> 6;
    const int qd = lane >> 4, lr = lane & 15;
    const int wm = (wave & 1) * 64, wn = (wave >> 1) * 64;

    const int srow = tid >> 3;                       // 0..31
    const int sgr  = ((tid & 7) ^ (srow & 7)) * 8;   // swizzled global granule
    const bf16* gA = A  + (size_t)(m0 + srow)*512 + sgr;
    const bf16* gB = BT + (size_t)(n0 + srow)*512 + sgr;
    bf16* lA = As + wave*512;
    bf16* lB = Bs + wave*512;

    for (int k0 = 0; k0 < 512; k0 += 64) {
        __syncthreads();
        #pragma unroll
        for (int i=0;i<4;i++) {
            async16p(gA + k0 + (size_t)i*32*512, lA + i*2048);
            async16p(gB + k0 + (size_t)i*32*512, lB + i*2048);
        }
        __syncthreads();
        #pragma unroll
        for (int half=0; half<2; ++half) {
            bf16x8 af[4], bfr[4];
            #pragma unroll
            for (int mi=0;mi<4;mi++) {
                int row = wm + mi*16 + lr;
                af[mi] = *(bf16x8*)(As + row*64 + (((half*4+qd)^(lr&7))*8));
            }
            #pragma unroll
            for (int ni=0;ni<4;ni++) {
                int row = wn + ni*16 + lr;
                bfr[ni] = *(bf16x8*)(Bs + row*64 + (((half*4+qd)^(lr&7))*8));
            }
            #pragma unroll
            for (int mi=0;mi<4;mi++)
              #pragma unroll
              for (int ni=0;ni<4;ni++)
                acc[mi][ni] = MFMA16(af[mi], bfr[ni], acc[mi][ni]);
        }
    }
}

// ------- gemm_o: G = Obf@WoT + bo; xb = Obf + gelu(G)  (bf16 out) ----------
__global__ __launch_bounds__(256, 4) void gemm_o_kernel(
    const bf16* __restrict__ Obf, const bf16* __restrict__ WoT,
    const float* __restrict__ bo, bf16* __restrict__ xb)
{
    __shared__ __align__(16) char smem[32768];
    const int m0 = blockIdx.x * 128, n0 = blockIdx.y * 128;
    const int tid = threadIdx.x;
    const int lane = tid & 63, wave = tid >> 6;
    const int qd = lane >> 4, lr = lane & 15;
    const int wm = (wave & 1) * 64, wn = (wave >> 1) * 64;

    f32x4 acc[4][4];
    #pragma unroll
    for (int i=0;i<4;i++)
      #pragma unroll
      for (int j=0;j<4;j++) acc[i][j] = (f32x4){0,0,0,0};

    gemm_core(Obf, WoT, m0, n0, smem, acc);

    #pragma unroll
    for (int ni=0;ni<4;ni++) {
        int n = n0 + wn + ni*16 + lr;
        float bv = bo[n];
        #pragma unroll
        for (int mi=0;mi<4;mi++) {
            int mb = m0 + wm + mi*16 + qd*4;
            #pragma unroll
            for (int r=0;r<4;r++) {
                float g = acc[mi][ni][r] + bv;
                float gelu = 0.5f * g * (1.f + erff(g * 0.70710678118654752f));
                size_t idx = (size_t)(mb+r)*512 + n;
                xb[idx] = (bf16)((float)Obf[idx] + gelu);
            }
        }
    }
}

// ---------------- ln1: out = LN(xb) ----------------
__global__ __launch_bounds__(256) void ln1_kernel(
    const bf16* __restrict__ xb, float* __restrict__ out)
{
    const int wave = threadIdx.x >> 6, lane = threadIdx.x & 63;
    const int row = blockIdx.x*4 + wave;
    const size_t base = (size_t)row*512 + lane*8;
    bf16x8 xv = *(const bf16x8*)(xb + base);
    float x[8];
    #pragma unroll
    for (int i=0;i<8;i++) x[i] = (float)xv[i];
    float s1 = 0.f, s2 = 0.f;
    #pragma unroll
    for (int i=0;i<8;i++){ s1 += x[i]; s2 += x[i]*x[i]; }
    #pragma unroll
    for (int off=1; off<64; off<<=1) { s1 += __shfl_xor(s1, off); s2 += __shfl_xor(s2, off); }
    float mu  = s1 * (1.f/512.f);
    float var = s2 * (1.f/512.f) - mu*mu;
    float rstd = rsqrtf(var + 1e-5f);
    float4 o0 = {(x[0]-mu)*rstd,(x[1]-mu)*rstd,(x[2]-mu)*rstd,(x[3]-mu)*rstd};
    float4 o1 = {(x[4]-mu)*rstd,(x[5]-mu)*rstd,(x[6]-mu)*rstd,(x[7]-mu)*rstd};
    *(float4*)(out + base)     = o0;
    *(float4*)(out + base + 4) = o1;
}

extern "C" void kernel_launch(void* const* d_in, const int* in_sizes, int n_in,
                              void* d_out, int out_size, void* d_ws, size_t ws_size,
                              hipStream_t stream)
{
    (void)in_sizes; (void)n_in; (void)out_size; (void)ws_size;
    const float* Q  = (const float*)d_in[0];
    const float* K  = (const float*)d_in[1];
    const float* Wq = (const float*)d_in[2];
    const float* bq = (const float*)d_in[3];
    const float* Wk = (const float*)d_in[4];
    const float* bk = (const float*)d_in[5];
    const float* Wv = (const float*)d_in[6];
    const float* bv = (const float*)d_in[7];
    const float* Wo = (const float*)d_in[8];
    const float* bo = (const float*)d_in[9];
    float* out = (float*)d_out;

    const size_t nTok = (size_t)16*1024*512;
    char* p = (char*)d_ws;
    auto alloc = [&](size_t bytes)->char* {
        char* r = p; p += (bytes + 255) & ~(size_t)255; return r;
    };
    bf16* WqT   = (bf16*)alloc(512*512*2);
    bf16* WkT   = (bf16*)alloc(512*512*2);
    bf16* WvT   = (bf16*)alloc(512*512*2);
    bf16* WoT   = (bf16*)alloc(512*512*2);
    bf16* qbb   = (bf16*)alloc(nTok*2);
    bf16* kbb   = (bf16*)alloc(nTok*2);
    bf16* vT    = (bf16*)alloc(nTok*2);
    bf16* attnb = (bf16*)alloc(nTok*2);
    bf16* Obf   = (bf16*)alloc(nTok*2);
    bf16* xb    = (bf16*)alloc(nTok*2);

    prep_w_kernel<<<1024, 256, 0, stream>>>(Wq, Wk, Wv, Wo, WqT, WkT, WvT, WoT);
    gemm_qkv_kernel<<<dim3(128,4,3), 256, 0, stream>>>(Q, K, WqT, WkT, WvT,
                                                       bq, bk, bv, qbb, kbb, vT);
    attn_kernel<<<dim3(8,8,16), 256, 0, stream>>>(qbb, kbb, vT, attnb);
    ln0_kernel<<<4096, 256, 0, stream>>>(attnb, Obf);
    gemm_o_kernel<<<dim3(128,4), 256, 0, stream>>>(Obf, WoT, bo, xb);
    ln1_kernel<<<4096, 256, 0, stream>>>(xb, out);
}